// Round 6
// baseline (945.902 us; speedup 1.0000x reference)
//
#include <hip/hip_runtime.h>

#define H 128
#define LN_EPS 1e-5f

typedef __attribute__((ext_vector_type(8))) short bf16x8;
typedef __attribute__((ext_vector_type(4))) float f32x4;

__device__ __forceinline__ ushort f2bf(float f) {
    unsigned u = __builtin_bit_cast(unsigned, f);
    u += 0x7fffu + ((u >> 16) & 1u);          // RNE
    return (ushort)(u >> 16);
}

// pack 8 fp32 -> bf16x8 via v_cvt_pk_bf16_f32 (RNE)
__device__ __forceinline__ bf16x8 cvt8(float4 lo, float4 hi) {
    union { bf16x8 v; unsigned u[4]; } r;
    asm("v_cvt_pk_bf16_f32 %0, %1, %2" : "=v"(r.u[0]) : "v"(lo.x), "v"(lo.y));
    asm("v_cvt_pk_bf16_f32 %0, %1, %2" : "=v"(r.u[1]) : "v"(lo.z), "v"(lo.w));
    asm("v_cvt_pk_bf16_f32 %0, %1, %2" : "=v"(r.u[2]) : "v"(hi.x), "v"(hi.y));
    asm("v_cvt_pk_bf16_f32 %0, %1, %2" : "=v"(r.u[3]) : "v"(hi.z), "v"(hi.w));
    return r.v;
}

__device__ __forceinline__ f32x4 mfma16(bf16x8 a, bf16x8 b, f32x4 c) {
    return __builtin_amdgcn_mfma_f32_16x16x32_bf16(a, b, c, 0, 0, 0);
}

// ---------------------------------------------------------------------------
// counting-sort by destination, then gather-sum (replaces atomic scatter)
// ---------------------------------------------------------------------------
__global__ __launch_bounds__(256) void hist_kernel(
    const int* __restrict__ ei, int* __restrict__ cnt, int E)
{
    int i = blockIdx.x * 256 + threadIdx.x;
    if (i < E) atomicAdd(&cnt[ei[E + i]], 1);
}

__global__ __launch_bounds__(1024) void scan_kernel(
    const int* __restrict__ cnt, int* __restrict__ off,
    int* __restrict__ cursor, int N)
{
    __shared__ int s[1024];
    const int t = threadIdx.x;
    const int chunk = (N + 1023) / 1024;
    const int lo = t * chunk, hi = min(lo + chunk, N);
    int sum = 0;
    for (int i = lo; i < hi; ++i) sum += cnt[i];
    s[t] = sum;
    __syncthreads();
    for (int d = 1; d < 1024; d <<= 1) {
        int v = (t >= d) ? s[t - d] : 0;
        __syncthreads();
        s[t] += v;
        __syncthreads();
    }
    int running = s[t] - sum;
    for (int i = lo; i < hi; ++i) {
        off[i] = running;
        cursor[i] = running;
        running += cnt[i];
    }
    if (t == 1023) off[N] = running;
}

__global__ __launch_bounds__(256) void reorder_kernel(
    const int* __restrict__ ei, int* __restrict__ cursor,
    int* __restrict__ sorted, int E)
{
    int i = blockIdx.x * 256 + threadIdx.x;
    if (i < E) {
        int pos = atomicAdd(&cursor[ei[E + i]], 1);
        sorted[pos] = i;
    }
}

__global__ __launch_bounds__(256) void segsum_kernel(
    const float* __restrict__ e, const int* __restrict__ sorted,
    const int* __restrict__ off, float* __restrict__ msgs, int N)
{
    int node = blockIdx.x * 4 + (threadIdx.x >> 6);
    int lane = threadIdx.x & 63;
    if (node >= N) return;
    int beg = off[node], end = off[node + 1];
    float ax = 0.f, ay = 0.f;
    for (int base = beg; base < end; base += 64) {
        int eid_l = (base + lane < end) ? sorted[base + lane] : 0;
        int cnt = min(64, end - base);
        int i = 0;
        for (; i + 4 <= cnt; i += 4) {
            int e0 = __shfl(eid_l, i), e1 = __shfl(eid_l, i + 1);
            int e2 = __shfl(eid_l, i + 2), e3 = __shfl(eid_l, i + 3);
            float2 v0 = *reinterpret_cast<const float2*>(e + (size_t)e0 * H + lane * 2);
            float2 v1 = *reinterpret_cast<const float2*>(e + (size_t)e1 * H + lane * 2);
            float2 v2 = *reinterpret_cast<const float2*>(e + (size_t)e2 * H + lane * 2);
            float2 v3 = *reinterpret_cast<const float2*>(e + (size_t)e3 * H + lane * 2);
            ax += v0.x + v1.x + v2.x + v3.x;
            ay += v0.y + v1.y + v2.y + v3.y;
        }
        for (; i < cnt; ++i) {
            int eid = __shfl(eid_l, i);
            float2 v = *reinterpret_cast<const float2*>(e + (size_t)eid * H + lane * 2);
            ax += v.x; ay += v.y;
        }
    }
    *reinterpret_cast<float2*>(msgs + (size_t)node * H + lane * 2) = make_float2(ax, ay);
}

// ---------------------------------------------------------------------------
// W[K][128] fp32 -> Wt[128][K] bf16
// ---------------------------------------------------------------------------
__global__ __launch_bounds__(256) void wtrans_kernel(
    const float* __restrict__ W, ushort* __restrict__ Wt, int K)
{
    int idx = blockIdx.x * 256 + threadIdx.x;
    if (idx >= K * H) return;
    int k = idx >> 7, n = idx & (H - 1);
    Wt[n * K + k] = f2bf(W[idx]);
}

// ---------------------------------------------------------------------------
// Node MLP: [x|msgs](256) -> L1 -> LN -> SiLU -> L2 -> +x. Emits xbf too.
// ---------------------------------------------------------------------------
__global__ __launch_bounds__(256, 4) void node_mlp_kernel(
    const float* __restrict__ x, const float* __restrict__ msgs,
    const ushort* __restrict__ W1t, const float* __restrict__ b1,
    const float* __restrict__ g1, const float* __restrict__ be1,
    const ushort* __restrict__ W2t, const float* __restrict__ b2,
    float* __restrict__ x_out, ushort* __restrict__ xbf, int N)
{
    __shared__ ushort smem[64 * 264];           // in staged; h [64][136] aliases
    __shared__ float part_s[2][64], part_q[2][64];

    const int tid = threadIdx.x;
    const int row0 = blockIdx.x * 64;

    for (int idx = tid; idx < 64 * 64; idx += 256) {
        int r = idx >> 6, c4 = idx & 63;
        int row = row0 + r;
        float4 v = make_float4(0.f, 0.f, 0.f, 0.f);
        if (row < N)
            v = (c4 < 32) ? reinterpret_cast<const float4*>(x + (size_t)row * H)[c4]
                          : reinterpret_cast<const float4*>(msgs + (size_t)row * H)[c4 - 32];
        ushort4 bv;
        bv.x = f2bf(v.x); bv.y = f2bf(v.y); bv.z = f2bf(v.z); bv.w = f2bf(v.w);
        *reinterpret_cast<ushort4*>(&smem[r * 264 + c4 * 4]) = bv;
    }
    __syncthreads();

    const int lane = tid & 63, w = tid >> 6;
    const int l15 = lane & 15, lg = lane >> 4;
    const int mrow = (w & 1) * 32, ncol = (w >> 1) * 64;

    const ushort* pi0 = smem + (size_t)(mrow + l15) * 264;
    const ushort* pi1 = smem + (size_t)(mrow + 16 + l15) * 264;
    const ushort* pw1 = W1t + (size_t)(ncol + l15) * 256;

    f32x4 acc[2][4];
    #pragma unroll
    for (int mt = 0; mt < 2; ++mt)
        #pragma unroll
        for (int nt = 0; nt < 4; ++nt)
            acc[mt][nt] = (f32x4){0.f, 0.f, 0.f, 0.f};

    #pragma unroll
    for (int ks = 0; ks < 8; ++ks) {
        int k0 = ks * 32 + lg * 8;
        bf16x8 a0 = *reinterpret_cast<const bf16x8*>(pi0 + k0);
        bf16x8 a1 = *reinterpret_cast<const bf16x8*>(pi1 + k0);
        #pragma unroll
        for (int nt = 0; nt < 4; ++nt) {
            bf16x8 bfr = *reinterpret_cast<const bf16x8*>(pw1 + (size_t)nt * 16 * 256 + k0);
            acc[0][nt] = mfma16(a0, bfr, acc[0][nt]);
            acc[1][nt] = mfma16(a1, bfr, acc[1][nt]);
        }
    }

    float b1c[4], g1c[4], be1c[4];
    #pragma unroll
    for (int nt = 0; nt < 4; ++nt) {
        int c = ncol + nt * 16 + l15;
        b1c[nt] = b1[c]; g1c[nt] = g1[c]; be1c[nt] = be1[c];
    }
    #pragma unroll
    for (int mt = 0; mt < 2; ++mt)
        #pragma unroll
        for (int nt = 0; nt < 4; ++nt)
            #pragma unroll
            for (int r = 0; r < 4; ++r)
                acc[mt][nt][r] += b1c[nt];

    #pragma unroll
    for (int mt = 0; mt < 2; ++mt) {
        #pragma unroll
        for (int r = 0; r < 4; ++r) {
            float s = acc[mt][0][r] + acc[mt][1][r] + acc[mt][2][r] + acc[mt][3][r];
            float q = acc[mt][0][r] * acc[mt][0][r] + acc[mt][1][r] * acc[mt][1][r]
                    + acc[mt][2][r] * acc[mt][2][r] + acc[mt][3][r] * acc[mt][3][r];
            #pragma unroll
            for (int m = 8; m >= 1; m >>= 1) {
                s += __shfl_xor(s, m);
                q += __shfl_xor(q, m);
            }
            if (l15 == 0) {
                int rl = mrow + mt * 16 + lg * 4 + r;
                part_s[w >> 1][rl] = s;
                part_q[w >> 1][rl] = q;
            }
        }
    }
    __syncthreads();

    #pragma unroll
    for (int mt = 0; mt < 2; ++mt) {
        #pragma unroll
        for (int r = 0; r < 4; ++r) {
            int rl = mrow + mt * 16 + lg * 4 + r;
            float s  = part_s[0][rl] + part_s[1][rl];
            float q  = part_q[0][rl] + part_q[1][rl];
            float mu = s * (1.0f / H);
            float rs = rsqrtf(q * (1.0f / H) - mu * mu + LN_EPS);
            #pragma unroll
            for (int nt = 0; nt < 4; ++nt) {
                float v = (acc[mt][nt][r] - mu) * rs * g1c[nt] + be1c[nt];
                v = v / (1.0f + __expf(-v));
                smem[rl * 136 + ncol + nt * 16 + l15] = f2bf(v);
            }
        }
    }
    __syncthreads();

    const ushort* ph0 = smem + (size_t)(mrow + l15) * 136;
    const ushort* ph1 = smem + (size_t)(mrow + 16 + l15) * 136;
    const ushort* pw2 = W2t + (size_t)(ncol + l15) * 128;

    f32x4 acc2[2][4];
    #pragma unroll
    for (int nt = 0; nt < 4; ++nt) {
        float bb = b2[ncol + nt * 16 + l15];
        #pragma unroll
        for (int mt = 0; mt < 2; ++mt)
            acc2[mt][nt] = (f32x4){bb, bb, bb, bb};
    }
    #pragma unroll
    for (int ks = 0; ks < 4; ++ks) {
        int k0 = ks * 32 + lg * 8;
        bf16x8 a0 = *reinterpret_cast<const bf16x8*>(ph0 + k0);
        bf16x8 a1 = *reinterpret_cast<const bf16x8*>(ph1 + k0);
        #pragma unroll
        for (int nt = 0; nt < 4; ++nt) {
            bf16x8 bfr = *reinterpret_cast<const bf16x8*>(pw2 + (size_t)nt * 16 * 128 + k0);
            acc2[0][nt] = mfma16(a0, bfr, acc2[0][nt]);
            acc2[1][nt] = mfma16(a1, bfr, acc2[1][nt]);
        }
    }

    #pragma unroll
    for (int mt = 0; mt < 2; ++mt) {
        #pragma unroll
        for (int r = 0; r < 4; ++r) {
            int row = row0 + mrow + mt * 16 + lg * 4 + r;
            if (row < N) {
                const float* rp = x + (size_t)row * H;
                float* op = x_out + (size_t)row * H;
                ushort* bp = xbf + (size_t)row * H;
                #pragma unroll
                for (int nt = 0; nt < 4; ++nt) {
                    int c = ncol + nt * 16 + l15;
                    float o = acc2[mt][nt][r] + rp[c];
                    op[c] = o;
                    bp[c] = f2bf(o);
                }
            }
        }
    }
}

// ---------------------------------------------------------------------------
// Edge MLP: [xbf[s]|xbf[d]|e](384) -> L1 -> LN -> SiLU -> L2 -> +e.
// No e-staging: e read per-lane fp32 as A-frags + cvt_pk.  All x gathers
// burst-issued and fenced with sched_barrier(0).  LDS holds h only.
// ---------------------------------------------------------------------------
__global__ __launch_bounds__(256, 3) void edge_mlp_kernel(
    const ushort* __restrict__ xbf, const float* __restrict__ e,
    const int* __restrict__ ei,
    const ushort* __restrict__ W1t, const float* __restrict__ b1,
    const float* __restrict__ g1, const float* __restrict__ be1,
    const ushort* __restrict__ W2t, const float* __restrict__ b2,
    float* __restrict__ e_out, int E)
{
    __shared__ ushort h_s[64 * 136];            // 17.4 KB
    __shared__ float part_s[2][64], part_q[2][64];

    const int tid = threadIdx.x;
    const int row0 = blockIdx.x * 64;
    const int lane = tid & 63, w = tid >> 6;
    const int l15 = lane & 15, lg = lane >> 4;
    const int mrow = (w & 1) * 32, ncol = (w >> 1) * 64;
    const int rA0 = mrow + l15, rA1 = mrow + 16 + l15;
    const int gr0 = min(row0 + rA0, E - 1);
    const int gr1 = min(row0 + rA1, E - 1);

    // per-lane edge endpoint indices (16-lane groups read 64B coalesced)
    const int s0 = ei[gr0], s1 = ei[gr1];
    const int d0 = ei[E + gr0], d1 = ei[E + gr1];

    const ushort* ps0 = xbf + (size_t)s0 * H + lg * 8;
    const ushort* ps1 = xbf + (size_t)s1 * H + lg * 8;
    const ushort* pd0 = xbf + (size_t)d0 * H + lg * 8;
    const ushort* pd1 = xbf + (size_t)d1 * H + lg * 8;
    const float*  qe0 = e + (size_t)gr0 * H + lg * 8;
    const float*  qe1 = e + (size_t)gr1 * H + lg * 8;

    // ---- burst: 16 x-gathers + first half of e loads, fenced ----
    bf16x8 xs0[4], xs1[4], xd0[4], xd1[4];
    #pragma unroll
    for (int t = 0; t < 4; ++t) {
        xs0[t] = *reinterpret_cast<const bf16x8*>(ps0 + t * 32);
        xs1[t] = *reinterpret_cast<const bf16x8*>(ps1 + t * 32);
        xd0[t] = *reinterpret_cast<const bf16x8*>(pd0 + t * 32);
        xd1[t] = *reinterpret_cast<const bf16x8*>(pd1 + t * 32);
    }
    float4 e0a[2], e0b[2], e1a[2], e1b[2];      // e chunks t=0,1
    #pragma unroll
    for (int t = 0; t < 2; ++t) {
        e0a[t] = *reinterpret_cast<const float4*>(qe0 + t * 32);
        e0b[t] = *reinterpret_cast<const float4*>(qe0 + t * 32 + 4);
        e1a[t] = *reinterpret_cast<const float4*>(qe1 + t * 32);
        e1b[t] = *reinterpret_cast<const float4*>(qe1 + t * 32 + 4);
    }
    __builtin_amdgcn_sched_barrier(0);          // keep the burst issued first

    const ushort* pw1 = W1t + (size_t)(ncol + l15) * 384 + lg * 8;

    f32x4 acc[2][4];
    #pragma unroll
    for (int mt = 0; mt < 2; ++mt)
        #pragma unroll
        for (int nt = 0; nt < 4; ++nt)
            acc[mt][nt] = (f32x4){0.f, 0.f, 0.f, 0.f};

    // ---- mm1: x-src (ks 0..3) ----
    #pragma unroll
    for (int t = 0; t < 4; ++t) {
        #pragma unroll
        for (int nt = 0; nt < 4; ++nt) {
            bf16x8 bfr = *reinterpret_cast<const bf16x8*>(pw1 + (size_t)nt * 16 * 384 + t * 32);
            acc[0][nt] = mfma16(xs0[t], bfr, acc[0][nt]);
            acc[1][nt] = mfma16(xs1[t], bfr, acc[1][nt]);
        }
    }

    // issue remaining e loads (chunks t=2,3) while x-dst MFMAs run
    float4 e0a2[2], e0b2[2], e1a2[2], e1b2[2];
    #pragma unroll
    for (int t = 0; t < 2; ++t) {
        e0a2[t] = *reinterpret_cast<const float4*>(qe0 + (t + 2) * 32);
        e0b2[t] = *reinterpret_cast<const float4*>(qe0 + (t + 2) * 32 + 4);
        e1a2[t] = *reinterpret_cast<const float4*>(qe1 + (t + 2) * 32);
        e1b2[t] = *reinterpret_cast<const float4*>(qe1 + (t + 2) * 32 + 4);
    }

    // ---- mm1: x-dst (ks 4..7) ----
    #pragma unroll
    for (int t = 0; t < 4; ++t) {
        #pragma unroll
        for (int nt = 0; nt < 4; ++nt) {
            bf16x8 bfr = *reinterpret_cast<const bf16x8*>(pw1 + (size_t)nt * 16 * 384 + (4 + t) * 32);
            acc[0][nt] = mfma16(xd0[t], bfr, acc[0][nt]);
            acc[1][nt] = mfma16(xd1[t], bfr, acc[1][nt]);
        }
    }

    // ---- mm1: e (ks 8..11) ----
    #pragma unroll
    for (int t = 0; t < 2; ++t) {
        bf16x8 a0 = cvt8(e0a[t], e0b[t]);
        bf16x8 a1 = cvt8(e1a[t], e1b[t]);
        #pragma unroll
        for (int nt = 0; nt < 4; ++nt) {
            bf16x8 bfr = *reinterpret_cast<const bf16x8*>(pw1 + (size_t)nt * 16 * 384 + (8 + t) * 32);
            acc[0][nt] = mfma16(a0, bfr, acc[0][nt]);
            acc[1][nt] = mfma16(a1, bfr, acc[1][nt]);
        }
    }
    #pragma unroll
    for (int t = 0; t < 2; ++t) {
        bf16x8 a0 = cvt8(e0a2[t], e0b2[t]);
        bf16x8 a1 = cvt8(e1a2[t], e1b2[t]);
        #pragma unroll
        for (int nt = 0; nt < 4; ++nt) {
            bf16x8 bfr = *reinterpret_cast<const bf16x8*>(pw1 + (size_t)nt * 16 * 384 + (10 + t) * 32);
            acc[0][nt] = mfma16(a0, bfr, acc[0][nt]);
            acc[1][nt] = mfma16(a1, bfr, acc[1][nt]);
        }
    }

    // ---- bias + LN stats ----
    float b1c[4], g1c[4], be1c[4];
    #pragma unroll
    for (int nt = 0; nt < 4; ++nt) {
        int c = ncol + nt * 16 + l15;
        b1c[nt] = b1[c]; g1c[nt] = g1[c]; be1c[nt] = be1[c];
    }
    #pragma unroll
    for (int mt = 0; mt < 2; ++mt)
        #pragma unroll
        for (int nt = 0; nt < 4; ++nt)
            #pragma unroll
            for (int r = 0; r < 4; ++r)
                acc[mt][nt][r] += b1c[nt];

    #pragma unroll
    for (int mt = 0; mt < 2; ++mt) {
        #pragma unroll
        for (int r = 0; r < 4; ++r) {
            float s = acc[mt][0][r] + acc[mt][1][r] + acc[mt][2][r] + acc[mt][3][r];
            float q = acc[mt][0][r] * acc[mt][0][r] + acc[mt][1][r] * acc[mt][1][r]
                    + acc[mt][2][r] * acc[mt][2][r] + acc[mt][3][r] * acc[mt][3][r];
            #pragma unroll
            for (int m = 8; m >= 1; m >>= 1) {
                s += __shfl_xor(s, m);
                q += __shfl_xor(q, m);
            }
            if (l15 == 0) {
                int rl = mrow + mt * 16 + lg * 4 + r;
                part_s[w >> 1][rl] = s;
                part_q[w >> 1][rl] = q;
            }
        }
    }
    __syncthreads();

    // ---- LN + SiLU -> h in LDS ----
    #pragma unroll
    for (int mt = 0; mt < 2; ++mt) {
        #pragma unroll
        for (int r = 0; r < 4; ++r) {
            int rl = mrow + mt * 16 + lg * 4 + r;
            float s  = part_s[0][rl] + part_s[1][rl];
            float q  = part_q[0][rl] + part_q[1][rl];
            float mu = s * (1.0f / H);
            float rs = rsqrtf(q * (1.0f / H) - mu * mu + LN_EPS);
            #pragma unroll
            for (int nt = 0; nt < 4; ++nt) {
                float v = (acc[mt][nt][r] - mu) * rs * g1c[nt] + be1c[nt];
                v = v / (1.0f + __expf(-v));
                h_s[rl * 136 + ncol + nt * 16 + l15] = f2bf(v);
            }
        }
    }
    __syncthreads();

    // ---- mm2 ----
    const ushort* ph0 = h_s + (size_t)rA0 * 136;
    const ushort* ph1 = h_s + (size_t)rA1 * 136;
    const ushort* pw2 = W2t + (size_t)(ncol + l15) * 128;

    f32x4 acc2[2][4];
    #pragma unroll
    for (int nt = 0; nt < 4; ++nt) {
        float bb = b2[ncol + nt * 16 + l15];
        #pragma unroll
        for (int mt = 0; mt < 2; ++mt)
            acc2[mt][nt] = (f32x4){bb, bb, bb, bb};
    }
    #pragma unroll
    for (int ks = 0; ks < 4; ++ks) {
        int k0 = ks * 32 + lg * 8;
        bf16x8 a0 = *reinterpret_cast<const bf16x8*>(ph0 + k0);
        bf16x8 a1 = *reinterpret_cast<const bf16x8*>(ph1 + k0);
        #pragma unroll
        for (int nt = 0; nt < 4; ++nt) {
            bf16x8 bfr = *reinterpret_cast<const bf16x8*>(pw2 + (size_t)nt * 16 * 128 + k0);
            acc2[0][nt] = mfma16(a0, bfr, acc2[0][nt]);
            acc2[1][nt] = mfma16(a1, bfr, acc2[1][nt]);
        }
    }

    // ---- residual + store ----
    #pragma unroll
    for (int mt = 0; mt < 2; ++mt) {
        #pragma unroll
        for (int r = 0; r < 4; ++r) {
            int row = row0 + mrow + mt * 16 + lg * 4 + r;
            if (row < E) {
                const float* rp = e + (size_t)row * H;
                float* op = e_out + (size_t)row * H;
                #pragma unroll
                for (int nt = 0; nt < 4; ++nt) {
                    int c = ncol + nt * 16 + l15;
                    op[c] = acc2[mt][nt][r] + rp[c];
                }
            }
        }
    }
}

// ---------------------------------------------------------------------------
extern "C" void kernel_launch(void* const* d_in, const int* in_sizes, int n_in,
                              void* d_out, int out_size, void* d_ws, size_t ws_size,
                              hipStream_t stream)
{
    const float* x     = (const float*)d_in[0];
    const int*   ei    = (const int*)  d_in[1];
    const float* e     = (const float*)d_in[2];
    const float* Wn1   = (const float*)d_in[3];
    const float* bn1   = (const float*)d_in[4];
    const float* gn1   = (const float*)d_in[5];
    const float* betan1= (const float*)d_in[6];
    const float* Wn2   = (const float*)d_in[7];
    const float* bn2   = (const float*)d_in[8];
    const float* We1   = (const float*)d_in[9];
    const float* be1   = (const float*)d_in[10];
    const float* ge1   = (const float*)d_in[11];
    const float* betae1= (const float*)d_in[12];
    const float* We2   = (const float*)d_in[13];
    const float* be2   = (const float*)d_in[14];

    const int N = in_sizes[0] / H;
    const int E = in_sizes[2] / H;

    float* x_out = (float*)d_out;
    float* e_out = (float*)d_out + (long long)N * H;

    char* p = (char*)d_ws;
    float*  msgs = (float*)p;            p += (size_t)N * H * sizeof(float);
    ushort* xbf  = (ushort*)p;           p += (size_t)N * H * sizeof(ushort);
    ushort* Wn1t = (ushort*)p;           p += (size_t)256 * H * sizeof(ushort);
    ushort* Wn2t = (ushort*)p;           p += (size_t)H * H * sizeof(ushort);
    ushort* We1t = (ushort*)p;           p += (size_t)384 * H * sizeof(ushort);
    ushort* We2t = (ushort*)p;           p += (size_t)H * H * sizeof(ushort);
    p = (char*)(((size_t)p + 15) & ~(size_t)15);
    int* cnt    = (int*)p;               p += (size_t)N * sizeof(int);
    int* off    = (int*)p;               p += ((size_t)N + 1) * sizeof(int);
    int* cursor = (int*)p;               p += (size_t)N * sizeof(int);
    int* sorted = (int*)p;               p += (size_t)E * sizeof(int);

    wtrans_kernel<<<(256 * H + 255) / 256, 256, 0, stream>>>(Wn1, Wn1t, 256);
    wtrans_kernel<<<(H * H + 255) / 256, 256, 0, stream>>>(Wn2, Wn2t, H);
    wtrans_kernel<<<(384 * H + 255) / 256, 256, 0, stream>>>(We1, We1t, 384);
    wtrans_kernel<<<(H * H + 255) / 256, 256, 0, stream>>>(We2, We2t, H);

    hipMemsetAsync(cnt, 0, (size_t)N * sizeof(int), stream);
    hist_kernel<<<(E + 255) / 256, 256, 0, stream>>>(ei, cnt, E);
    scan_kernel<<<1, 1024, 0, stream>>>(cnt, off, cursor, N);
    reorder_kernel<<<(E + 255) / 256, 256, 0, stream>>>(ei, cursor, sorted, E);
    segsum_kernel<<<(N + 3) / 4, 256, 0, stream>>>(e, sorted, off, msgs, N);

    {
        int blocks = (N + 63) / 64;
        node_mlp_kernel<<<blocks, 256, 0, stream>>>(
            x, msgs, Wn1t, bn1, gn1, betan1, Wn2t, bn2, x_out, xbf, N);
    }
    {
        int blocks = (E + 63) / 64;
        edge_mlp_kernel<<<blocks, 256, 0, stream>>>(
            xbf, e, ei, We1t, be1, ge1, betae1, We2t, be2, e_out, E);
    }
}

// Round 7
// 941.736 us; speedup vs baseline: 1.0044x; 1.0044x over previous
//
#include <hip/hip_runtime.h>

#define H 128
#define LN_EPS 1e-5f

typedef __attribute__((ext_vector_type(8))) short bf16x8;
typedef __attribute__((ext_vector_type(4))) float f32x4;

__device__ __forceinline__ ushort f2bf(float f) {
    unsigned u = __builtin_bit_cast(unsigned, f);
    u += 0x7fffu + ((u >> 16) & 1u);          // RNE
    return (ushort)(u >> 16);
}

__device__ __forceinline__ f32x4 mfma16(bf16x8 a, bf16x8 b, f32x4 c) {
    return __builtin_amdgcn_mfma_f32_16x16x32_bf16(a, b, c, 0, 0, 0);
}

// ---------------------------------------------------------------------------
// counting-sort by destination, then gather-sum (replaces atomic scatter)
// ---------------------------------------------------------------------------
__global__ __launch_bounds__(256) void hist_kernel(
    const int* __restrict__ ei, int* __restrict__ cnt, int E)
{
    int i = blockIdx.x * 256 + threadIdx.x;
    if (i < E) atomicAdd(&cnt[ei[E + i]], 1);
}

__global__ __launch_bounds__(1024) void scan_kernel(
    const int* __restrict__ cnt, int* __restrict__ off,
    int* __restrict__ cursor, int N)
{
    __shared__ int s[1024];
    const int t = threadIdx.x;
    const int chunk = (N + 1023) / 1024;
    const int lo = t * chunk, hi = min(lo + chunk, N);
    int sum = 0;
    for (int i = lo; i < hi; ++i) sum += cnt[i];
    s[t] = sum;
    __syncthreads();
    for (int d = 1; d < 1024; d <<= 1) {
        int v = (t >= d) ? s[t - d] : 0;
        __syncthreads();
        s[t] += v;
        __syncthreads();
    }
    int running = s[t] - sum;
    for (int i = lo; i < hi; ++i) {
        off[i] = running;
        cursor[i] = running;
        running += cnt[i];
    }
    if (t == 1023) off[N] = running;
}

__global__ __launch_bounds__(256) void reorder_kernel(
    const int* __restrict__ ei, int* __restrict__ cursor,
    int* __restrict__ sorted, int E)
{
    int i = blockIdx.x * 256 + threadIdx.x;
    if (i < E) {
        int pos = atomicAdd(&cursor[ei[E + i]], 1);
        sorted[pos] = i;
    }
}

__global__ __launch_bounds__(256) void segsum_kernel(
    const float* __restrict__ e, const int* __restrict__ sorted,
    const int* __restrict__ off, float* __restrict__ msgs, int N)
{
    int node = blockIdx.x * 4 + (threadIdx.x >> 6);
    int lane = threadIdx.x & 63;
    if (node >= N) return;
    int beg = off[node], end = off[node + 1];
    float ax = 0.f, ay = 0.f;
    for (int base = beg; base < end; base += 64) {
        int eid_l = (base + lane < end) ? sorted[base + lane] : 0;
        int cnt = min(64, end - base);
        int i = 0;
        for (; i + 4 <= cnt; i += 4) {
            int e0 = __shfl(eid_l, i), e1 = __shfl(eid_l, i + 1);
            int e2 = __shfl(eid_l, i + 2), e3 = __shfl(eid_l, i + 3);
            float2 v0 = *reinterpret_cast<const float2*>(e + (size_t)e0 * H + lane * 2);
            float2 v1 = *reinterpret_cast<const float2*>(e + (size_t)e1 * H + lane * 2);
            float2 v2 = *reinterpret_cast<const float2*>(e + (size_t)e2 * H + lane * 2);
            float2 v3 = *reinterpret_cast<const float2*>(e + (size_t)e3 * H + lane * 2);
            ax += v0.x + v1.x + v2.x + v3.x;
            ay += v0.y + v1.y + v2.y + v3.y;
        }
        for (; i < cnt; ++i) {
            int eid = __shfl(eid_l, i);
            float2 v = *reinterpret_cast<const float2*>(e + (size_t)eid * H + lane * 2);
            ax += v.x; ay += v.y;
        }
    }
    *reinterpret_cast<float2*>(msgs + (size_t)node * H + lane * 2) = make_float2(ax, ay);
}

// ---------------------------------------------------------------------------
// W[K][128] fp32 -> Wt[128][K] bf16
// ---------------------------------------------------------------------------
__global__ __launch_bounds__(256) void wtrans_kernel(
    const float* __restrict__ W, ushort* __restrict__ Wt, int K)
{
    int idx = blockIdx.x * 256 + threadIdx.x;
    if (idx >= K * H) return;
    int k = idx >> 7, n = idx & (H - 1);
    Wt[n * K + k] = f2bf(W[idx]);
}

// ---------------------------------------------------------------------------
// Node MLP: [x|msgs](256) -> L1 -> LN -> SiLU -> L2 -> +x. Emits xbf too.
// ---------------------------------------------------------------------------
__global__ __launch_bounds__(256, 4) void node_mlp_kernel(
    const float* __restrict__ x, const float* __restrict__ msgs,
    const ushort* __restrict__ W1t, const float* __restrict__ b1,
    const float* __restrict__ g1, const float* __restrict__ be1,
    const ushort* __restrict__ W2t, const float* __restrict__ b2,
    float* __restrict__ x_out, ushort* __restrict__ xbf, int N)
{
    __shared__ ushort smem[64 * 264];           // in staged; h [64][136] aliases
    __shared__ float part_s[2][64], part_q[2][64];

    const int tid = threadIdx.x;
    const int row0 = blockIdx.x * 64;

    for (int idx = tid; idx < 64 * 64; idx += 256) {
        int r = idx >> 6, c4 = idx & 63;
        int row = row0 + r;
        float4 v = make_float4(0.f, 0.f, 0.f, 0.f);
        if (row < N)
            v = (c4 < 32) ? reinterpret_cast<const float4*>(x + (size_t)row * H)[c4]
                          : reinterpret_cast<const float4*>(msgs + (size_t)row * H)[c4 - 32];
        ushort4 bv;
        bv.x = f2bf(v.x); bv.y = f2bf(v.y); bv.z = f2bf(v.z); bv.w = f2bf(v.w);
        *reinterpret_cast<ushort4*>(&smem[r * 264 + c4 * 4]) = bv;
    }
    __syncthreads();

    const int lane = tid & 63, w = tid >> 6;
    const int l15 = lane & 15, lg = lane >> 4;
    const int mrow = (w & 1) * 32, ncol = (w >> 1) * 64;

    const ushort* pi0 = smem + (size_t)(mrow + l15) * 264;
    const ushort* pi1 = smem + (size_t)(mrow + 16 + l15) * 264;
    const ushort* pw1 = W1t + (size_t)(ncol + l15) * 256;

    f32x4 acc[2][4];
    #pragma unroll
    for (int mt = 0; mt < 2; ++mt)
        #pragma unroll
        for (int nt = 0; nt < 4; ++nt)
            acc[mt][nt] = (f32x4){0.f, 0.f, 0.f, 0.f};

    #pragma unroll
    for (int ks = 0; ks < 8; ++ks) {
        int k0 = ks * 32 + lg * 8;
        bf16x8 a0 = *reinterpret_cast<const bf16x8*>(pi0 + k0);
        bf16x8 a1 = *reinterpret_cast<const bf16x8*>(pi1 + k0);
        #pragma unroll
        for (int nt = 0; nt < 4; ++nt) {
            bf16x8 bfr = *reinterpret_cast<const bf16x8*>(pw1 + (size_t)nt * 16 * 256 + k0);
            acc[0][nt] = mfma16(a0, bfr, acc[0][nt]);
            acc[1][nt] = mfma16(a1, bfr, acc[1][nt]);
        }
    }

    float b1c[4], g1c[4], be1c[4];
    #pragma unroll
    for (int nt = 0; nt < 4; ++nt) {
        int c = ncol + nt * 16 + l15;
        b1c[nt] = b1[c]; g1c[nt] = g1[c]; be1c[nt] = be1[c];
    }
    #pragma unroll
    for (int mt = 0; mt < 2; ++mt)
        #pragma unroll
        for (int nt = 0; nt < 4; ++nt)
            #pragma unroll
            for (int r = 0; r < 4; ++r)
                acc[mt][nt][r] += b1c[nt];

    #pragma unroll
    for (int mt = 0; mt < 2; ++mt) {
        #pragma unroll
        for (int r = 0; r < 4; ++r) {
            float s = acc[mt][0][r] + acc[mt][1][r] + acc[mt][2][r] + acc[mt][3][r];
            float q = acc[mt][0][r] * acc[mt][0][r] + acc[mt][1][r] * acc[mt][1][r]
                    + acc[mt][2][r] * acc[mt][2][r] + acc[mt][3][r] * acc[mt][3][r];
            #pragma unroll
            for (int m = 8; m >= 1; m >>= 1) {
                s += __shfl_xor(s, m);
                q += __shfl_xor(q, m);
            }
            if (l15 == 0) {
                int rl = mrow + mt * 16 + lg * 4 + r;
                part_s[w >> 1][rl] = s;
                part_q[w >> 1][rl] = q;
            }
        }
    }
    __syncthreads();

    #pragma unroll
    for (int mt = 0; mt < 2; ++mt) {
        #pragma unroll
        for (int r = 0; r < 4; ++r) {
            int rl = mrow + mt * 16 + lg * 4 + r;
            float s  = part_s[0][rl] + part_s[1][rl];
            float q  = part_q[0][rl] + part_q[1][rl];
            float mu = s * (1.0f / H);
            float rs = rsqrtf(q * (1.0f / H) - mu * mu + LN_EPS);
            #pragma unroll
            for (int nt = 0; nt < 4; ++nt) {
                float v = (acc[mt][nt][r] - mu) * rs * g1c[nt] + be1c[nt];
                v = v / (1.0f + __expf(-v));
                smem[rl * 136 + ncol + nt * 16 + l15] = f2bf(v);
            }
        }
    }
    __syncthreads();

    const ushort* ph0 = smem + (size_t)(mrow + l15) * 136;
    const ushort* ph1 = smem + (size_t)(mrow + 16 + l15) * 136;
    const ushort* pw2 = W2t + (size_t)(ncol + l15) * 128;

    f32x4 acc2[2][4];
    #pragma unroll
    for (int nt = 0; nt < 4; ++nt) {
        float bb = b2[ncol + nt * 16 + l15];
        #pragma unroll
        for (int mt = 0; mt < 2; ++mt)
            acc2[mt][nt] = (f32x4){bb, bb, bb, bb};
    }
    #pragma unroll
    for (int ks = 0; ks < 4; ++ks) {
        int k0 = ks * 32 + lg * 8;
        bf16x8 a0 = *reinterpret_cast<const bf16x8*>(ph0 + k0);
        bf16x8 a1 = *reinterpret_cast<const bf16x8*>(ph1 + k0);
        #pragma unroll
        for (int nt = 0; nt < 4; ++nt) {
            bf16x8 bfr = *reinterpret_cast<const bf16x8*>(pw2 + (size_t)nt * 16 * 128 + k0);
            acc2[0][nt] = mfma16(a0, bfr, acc2[0][nt]);
            acc2[1][nt] = mfma16(a1, bfr, acc2[1][nt]);
        }
    }

    #pragma unroll
    for (int mt = 0; mt < 2; ++mt) {
        #pragma unroll
        for (int r = 0; r < 4; ++r) {
            int row = row0 + mrow + mt * 16 + lg * 4 + r;
            if (row < N) {
                const float* rp = x + (size_t)row * H;
                float* op = x_out + (size_t)row * H;
                ushort* bp = xbf + (size_t)row * H;
                #pragma unroll
                for (int nt = 0; nt < 4; ++nt) {
                    int c = ncol + nt * 16 + l15;
                    float o = acc2[mt][nt][r] + rp[c];
                    op[c] = o;
                    bp[c] = f2bf(o);
                }
            }
        }
    }
}

// ---------------------------------------------------------------------------
// Edge MLP: [xbf[s]|xbf[d]|e](384) -> L1 -> LN -> SiLU -> L2 -> +e.
// e staged bf16 in LDS (high occupancy, coalesced).  16 x-gathers burst into
// registers, fenced; mm1 consumes the LDS e-part FIRST so the gathers' L2
// latency hides under 4 k-steps of MFMA, then ks0-7 run from registers.
// ---------------------------------------------------------------------------
__global__ __launch_bounds__(256, 4) void edge_mlp_kernel(
    const ushort* __restrict__ xbf, const float* __restrict__ e,
    const int* __restrict__ ei,
    const ushort* __restrict__ W1t, const float* __restrict__ b1,
    const float* __restrict__ g1, const float* __restrict__ be1,
    const ushort* __restrict__ W2t, const float* __restrict__ b2,
    float* __restrict__ e_out, int E)
{
    __shared__ ushort smem[64 * 136];           // e-part (phase1) / h (phase2)
    __shared__ float part_s[2][64], part_q[2][64];

    const int tid = threadIdx.x;
    const int row0 = blockIdx.x * 64;
    const int lane = tid & 63, w = tid >> 6;
    const int l15 = lane & 15, lg = lane >> 4;
    const int mrow = (w & 1) * 32, ncol = (w >> 1) * 64;
    const int rA0 = mrow + l15, rA1 = mrow + 16 + l15;
    const int gr0 = min(row0 + rA0, E - 1);
    const int gr1 = min(row0 + rA1, E - 1);

    // per-lane endpoint indices
    const int s0 = ei[gr0], s1 = ei[gr1];
    const int d0 = ei[E + gr0], d1 = ei[E + gr1];

    // ---- stage e rows -> bf16 LDS (coalesced float4) ----
    for (int idx = tid; idx < 64 * 32; idx += 256) {
        int r = idx >> 5, c4 = idx & 31;
        int row = row0 + r;
        float4 v = make_float4(0.f, 0.f, 0.f, 0.f);
        if (row < E)
            v = reinterpret_cast<const float4*>(e + (size_t)row * H)[c4];
        ushort4 bv;
        bv.x = f2bf(v.x); bv.y = f2bf(v.y); bv.z = f2bf(v.z); bv.w = f2bf(v.w);
        *reinterpret_cast<ushort4*>(&smem[r * 136 + c4 * 4]) = bv;
    }
    __syncthreads();

    const ushort* ps0 = xbf + (size_t)s0 * H + lg * 8;
    const ushort* ps1 = xbf + (size_t)s1 * H + lg * 8;
    const ushort* pd0 = xbf + (size_t)d0 * H + lg * 8;
    const ushort* pd1 = xbf + (size_t)d1 * H + lg * 8;

    // ---- burst: 16 x-gathers into registers, fenced ----
    bf16x8 xs0[4], xs1[4], xd0[4], xd1[4];
    #pragma unroll
    for (int t = 0; t < 4; ++t) {
        xs0[t] = *reinterpret_cast<const bf16x8*>(ps0 + t * 32);
        xs1[t] = *reinterpret_cast<const bf16x8*>(ps1 + t * 32);
        xd0[t] = *reinterpret_cast<const bf16x8*>(pd0 + t * 32);
        xd1[t] = *reinterpret_cast<const bf16x8*>(pd1 + t * 32);
    }
    __builtin_amdgcn_sched_barrier(0);          // gathers issue before mm1

    const ushort* pe0 = smem + (size_t)rA0 * 136 + lg * 8;
    const ushort* pe1 = smem + (size_t)rA1 * 136 + lg * 8;
    const ushort* pw1 = W1t + (size_t)(ncol + l15) * 384 + lg * 8;

    f32x4 acc[2][4];
    #pragma unroll
    for (int mt = 0; mt < 2; ++mt)
        #pragma unroll
        for (int nt = 0; nt < 4; ++nt)
            acc[mt][nt] = (f32x4){0.f, 0.f, 0.f, 0.f};

    // ---- mm1 part 1: e (global ks 8..11) from LDS — hides gather latency ----
    #pragma unroll
    for (int t = 0; t < 4; ++t) {
        bf16x8 a0 = *reinterpret_cast<const bf16x8*>(pe0 + t * 32);
        bf16x8 a1 = *reinterpret_cast<const bf16x8*>(pe1 + t * 32);
        #pragma unroll
        for (int nt = 0; nt < 4; ++nt) {
            bf16x8 bfr = *reinterpret_cast<const bf16x8*>(pw1 + (size_t)nt * 16 * 384 + (8 + t) * 32);
            acc[0][nt] = mfma16(a0, bfr, acc[0][nt]);
            acc[1][nt] = mfma16(a1, bfr, acc[1][nt]);
        }
    }

    // ---- mm1 part 2: x-src (ks 0..3) from registers ----
    #pragma unroll
    for (int t = 0; t < 4; ++t) {
        #pragma unroll
        for (int nt = 0; nt < 4; ++nt) {
            bf16x8 bfr = *reinterpret_cast<const bf16x8*>(pw1 + (size_t)nt * 16 * 384 + t * 32);
            acc[0][nt] = mfma16(xs0[t], bfr, acc[0][nt]);
            acc[1][nt] = mfma16(xs1[t], bfr, acc[1][nt]);
        }
    }

    // ---- mm1 part 3: x-dst (ks 4..7) from registers ----
    #pragma unroll
    for (int t = 0; t < 4; ++t) {
        #pragma unroll
        for (int nt = 0; nt < 4; ++nt) {
            bf16x8 bfr = *reinterpret_cast<const bf16x8*>(pw1 + (size_t)nt * 16 * 384 + (4 + t) * 32);
            acc[0][nt] = mfma16(xd0[t], bfr, acc[0][nt]);
            acc[1][nt] = mfma16(xd1[t], bfr, acc[1][nt]);
        }
    }

    // ---- bias + LN stats ----
    float b1c[4], g1c[4], be1c[4];
    #pragma unroll
    for (int nt = 0; nt < 4; ++nt) {
        int c = ncol + nt * 16 + l15;
        b1c[nt] = b1[c]; g1c[nt] = g1[c]; be1c[nt] = be1[c];
    }
    #pragma unroll
    for (int mt = 0; mt < 2; ++mt)
        #pragma unroll
        for (int nt = 0; nt < 4; ++nt)
            #pragma unroll
            for (int r = 0; r < 4; ++r)
                acc[mt][nt][r] += b1c[nt];

    #pragma unroll
    for (int mt = 0; mt < 2; ++mt) {
        #pragma unroll
        for (int r = 0; r < 4; ++r) {
            float s = acc[mt][0][r] + acc[mt][1][r] + acc[mt][2][r] + acc[mt][3][r];
            float q = acc[mt][0][r] * acc[mt][0][r] + acc[mt][1][r] * acc[mt][1][r]
                    + acc[mt][2][r] * acc[mt][2][r] + acc[mt][3][r] * acc[mt][3][r];
            #pragma unroll
            for (int m = 8; m >= 1; m >>= 1) {
                s += __shfl_xor(s, m);
                q += __shfl_xor(q, m);
            }
            if (l15 == 0) {
                int rl = mrow + mt * 16 + lg * 4 + r;
                part_s[w >> 1][rl] = s;
                part_q[w >> 1][rl] = q;
            }
        }
    }
    __syncthreads();   // also separates e-reads (above) from h-writes (below)

    // ---- LN + SiLU -> h in LDS ----
    #pragma unroll
    for (int mt = 0; mt < 2; ++mt) {
        #pragma unroll
        for (int r = 0; r < 4; ++r) {
            int rl = mrow + mt * 16 + lg * 4 + r;
            float s  = part_s[0][rl] + part_s[1][rl];
            float q  = part_q[0][rl] + part_q[1][rl];
            float mu = s * (1.0f / H);
            float rs = rsqrtf(q * (1.0f / H) - mu * mu + LN_EPS);
            #pragma unroll
            for (int nt = 0; nt < 4; ++nt) {
                float v = (acc[mt][nt][r] - mu) * rs * g1c[nt] + be1c[nt];
                v = v / (1.0f + __expf(-v));
                smem[rl * 136 + ncol + nt * 16 + l15] = f2bf(v);
            }
        }
    }
    __syncthreads();

    // ---- mm2 ----
    const ushort* ph0 = smem + (size_t)rA0 * 136;
    const ushort* ph1 = smem + (size_t)rA1 * 136;
    const ushort* pw2 = W2t + (size_t)(ncol + l15) * 128;

    f32x4 acc2[2][4];
    #pragma unroll
    for (int nt = 0; nt < 4; ++nt) {
        float bb = b2[ncol + nt * 16 + l15];
        #pragma unroll
        for (int mt = 0; mt < 2; ++mt)
            acc2[mt][nt] = (f32x4){bb, bb, bb, bb};
    }
    #pragma unroll
    for (int ks = 0; ks < 4; ++ks) {
        int k0 = ks * 32 + lg * 8;
        bf16x8 a0 = *reinterpret_cast<const bf16x8*>(ph0 + k0);
        bf16x8 a1 = *reinterpret_cast<const bf16x8*>(ph1 + k0);
        #pragma unroll
        for (int nt = 0; nt < 4; ++nt) {
            bf16x8 bfr = *reinterpret_cast<const bf16x8*>(pw2 + (size_t)nt * 16 * 128 + k0);
            acc2[0][nt] = mfma16(a0, bfr, acc2[0][nt]);
            acc2[1][nt] = mfma16(a1, bfr, acc2[1][nt]);
        }
    }

    // ---- residual + store ----
    #pragma unroll
    for (int mt = 0; mt < 2; ++mt) {
        #pragma unroll
        for (int r = 0; r < 4; ++r) {
            int row = row0 + mrow + mt * 16 + lg * 4 + r;
            if (row < E) {
                const float* rp = e + (size_t)row * H;
                float* op = e_out + (size_t)row * H;
                #pragma unroll
                for (int nt = 0; nt < 4; ++nt) {
                    int c = ncol + nt * 16 + l15;
                    op[c] = acc2[mt][nt][r] + rp[c];
                }
            }
        }
    }
}

// ---------------------------------------------------------------------------
extern "C" void kernel_launch(void* const* d_in, const int* in_sizes, int n_in,
                              void* d_out, int out_size, void* d_ws, size_t ws_size,
                              hipStream_t stream)
{
    const float* x     = (const float*)d_in[0];
    const int*   ei    = (const int*)  d_in[1];
    const float* e     = (const float*)d_in[2];
    const float* Wn1   = (const float*)d_in[3];
    const float* bn1   = (const float*)d_in[4];
    const float* gn1   = (const float*)d_in[5];
    const float* betan1= (const float*)d_in[6];
    const float* Wn2   = (const float*)d_in[7];
    const float* bn2   = (const float*)d_in[8];
    const float* We1   = (const float*)d_in[9];
    const float* be1   = (const float*)d_in[10];
    const float* ge1   = (const float*)d_in[11];
    const float* betae1= (const float*)d_in[12];
    const float* We2   = (const float*)d_in[13];
    const float* be2   = (const float*)d_in[14];

    const int N = in_sizes[0] / H;
    const int E = in_sizes[2] / H;

    float* x_out = (float*)d_out;
    float* e_out = (float*)d_out + (long long)N * H;

    char* p = (char*)d_ws;
    float*  msgs = (float*)p;            p += (size_t)N * H * sizeof(float);
    ushort* xbf  = (ushort*)p;           p += (size_t)N * H * sizeof(ushort);
    ushort* Wn1t = (ushort*)p;           p += (size_t)256 * H * sizeof(ushort);
    ushort* Wn2t = (ushort*)p;           p += (size_t)H * H * sizeof(ushort);
    ushort* We1t = (ushort*)p;           p += (size_t)384 * H * sizeof(ushort);
    ushort* We2t = (ushort*)p;           p += (size_t)H * H * sizeof(ushort);
    p = (char*)(((size_t)p + 15) & ~(size_t)15);
    int* cnt    = (int*)p;               p += (size_t)N * sizeof(int);
    int* off    = (int*)p;               p += ((size_t)N + 1) * sizeof(int);
    int* cursor = (int*)p;               p += (size_t)N * sizeof(int);
    int* sorted = (int*)p;               p += (size_t)E * sizeof(int);

    wtrans_kernel<<<(256 * H + 255) / 256, 256, 0, stream>>>(Wn1, Wn1t, 256);
    wtrans_kernel<<<(H * H + 255) / 256, 256, 0, stream>>>(Wn2, Wn2t, H);
    wtrans_kernel<<<(384 * H + 255) / 256, 256, 0, stream>>>(We1, We1t, 384);
    wtrans_kernel<<<(H * H + 255) / 256, 256, 0, stream>>>(We2, We2t, H);

    hipMemsetAsync(cnt, 0, (size_t)N * sizeof(int), stream);
    hist_kernel<<<(E + 255) / 256, 256, 0, stream>>>(ei, cnt, E);
    scan_kernel<<<1, 1024, 0, stream>>>(cnt, off, cursor, N);
    reorder_kernel<<<(E + 255) / 256, 256, 0, stream>>>(ei, cursor, sorted, E);
    segsum_kernel<<<(N + 3) / 4, 256, 0, stream>>>(e, sorted, off, msgs, N);

    {
        int blocks = (N + 63) / 64;
        node_mlp_kernel<<<blocks, 256, 0, stream>>>(
            x, msgs, Wn1t, bn1, gn1, betan1, Wn2t, bn2, x_out, xbf, N);
    }
    {
        int blocks = (E + 63) / 64;
        edge_mlp_kernel<<<blocks, 256, 0, stream>>>(
            xbf, e, ei, We1t, be1, ge1, betae1, We2t, be2, e_out, E);
    }
}

// Round 8
// 758.433 us; speedup vs baseline: 1.2472x; 1.2417x over previous
//
#include <hip/hip_runtime.h>

#define H 128
#define LN_EPS 1e-5f

typedef __attribute__((ext_vector_type(8))) short bf16x8;
typedef __attribute__((ext_vector_type(4))) float f32x4;

__device__ __forceinline__ ushort f2bf(float f) {
    unsigned u = __builtin_bit_cast(unsigned, f);
    u += 0x7fffu + ((u >> 16) & 1u);          // RNE
    return (ushort)(u >> 16);
}

__device__ __forceinline__ float bf2f(ushort u) {
    return __builtin_bit_cast(float, (unsigned)u << 16);
}

__device__ __forceinline__ f32x4 mfma16(bf16x8 a, bf16x8 b, f32x4 c) {
    return __builtin_amdgcn_mfma_f32_16x16x32_bf16(a, b, c, 0, 0, 0);
}

// ---------------------------------------------------------------------------
// counting-sort by destination, then gather-sum (replaces atomic scatter)
// ---------------------------------------------------------------------------
__global__ __launch_bounds__(256) void hist_kernel(
    const int* __restrict__ ei, int* __restrict__ cnt, int E)
{
    int i = blockIdx.x * 256 + threadIdx.x;
    if (i < E) atomicAdd(&cnt[ei[E + i]], 1);
}

__global__ __launch_bounds__(1024) void scan_kernel(
    const int* __restrict__ cnt, int* __restrict__ off,
    int* __restrict__ cursor, int N)
{
    __shared__ int s[1024];
    const int t = threadIdx.x;
    const int chunk = (N + 1023) / 1024;
    const int lo = t * chunk, hi = min(lo + chunk, N);
    int sum = 0;
    for (int i = lo; i < hi; ++i) sum += cnt[i];
    s[t] = sum;
    __syncthreads();
    for (int d = 1; d < 1024; d <<= 1) {
        int v = (t >= d) ? s[t - d] : 0;
        __syncthreads();
        s[t] += v;
        __syncthreads();
    }
    int running = s[t] - sum;
    for (int i = lo; i < hi; ++i) {
        off[i] = running;
        cursor[i] = running;
        running += cnt[i];
    }
    if (t == 1023) off[N] = running;
}

__global__ __launch_bounds__(256) void reorder_kernel(
    const int* __restrict__ ei, int* __restrict__ cursor,
    int* __restrict__ sorted, int E)
{
    int i = blockIdx.x * 256 + threadIdx.x;
    if (i < E) {
        int pos = atomicAdd(&cursor[ei[E + i]], 1);
        sorted[pos] = i;
    }
}

__global__ __launch_bounds__(256) void segsum_kernel(
    const float* __restrict__ e, const int* __restrict__ sorted,
    const int* __restrict__ off, float* __restrict__ msgs, int N)
{
    int node = blockIdx.x * 4 + (threadIdx.x >> 6);
    int lane = threadIdx.x & 63;
    if (node >= N) return;
    int beg = off[node], end = off[node + 1];
    float ax = 0.f, ay = 0.f;
    for (int base = beg; base < end; base += 64) {
        int eid_l = (base + lane < end) ? sorted[base + lane] : 0;
        int cnt = min(64, end - base);
        int i = 0;
        for (; i + 4 <= cnt; i += 4) {
            int e0 = __shfl(eid_l, i), e1 = __shfl(eid_l, i + 1);
            int e2 = __shfl(eid_l, i + 2), e3 = __shfl(eid_l, i + 3);
            float2 v0 = *reinterpret_cast<const float2*>(e + (size_t)e0 * H + lane * 2);
            float2 v1 = *reinterpret_cast<const float2*>(e + (size_t)e1 * H + lane * 2);
            float2 v2 = *reinterpret_cast<const float2*>(e + (size_t)e2 * H + lane * 2);
            float2 v3 = *reinterpret_cast<const float2*>(e + (size_t)e3 * H + lane * 2);
            ax += v0.x + v1.x + v2.x + v3.x;
            ay += v0.y + v1.y + v2.y + v3.y;
        }
        for (; i < cnt; ++i) {
            int eid = __shfl(eid_l, i);
            float2 v = *reinterpret_cast<const float2*>(e + (size_t)eid * H + lane * 2);
            ax += v.x; ay += v.y;
        }
    }
    *reinterpret_cast<float2*>(msgs + (size_t)node * H + lane * 2) = make_float2(ax, ay);
}

// ---------------------------------------------------------------------------
// W[K][128] fp32 -> Wt[128][K] bf16
// ---------------------------------------------------------------------------
__global__ __launch_bounds__(256) void wtrans_kernel(
    const float* __restrict__ W, ushort* __restrict__ Wt, int K)
{
    int idx = blockIdx.x * 256 + threadIdx.x;
    if (idx >= K * H) return;
    int k = idx >> 7, n = idx & (H - 1);
    Wt[n * K + k] = f2bf(W[idx]);
}

// ---------------------------------------------------------------------------
// Node MLP: [x|msgs](256) -> L1 -> LN -> SiLU -> L2 -> +x. Emits xbf too.
// ---------------------------------------------------------------------------
__global__ __launch_bounds__(256, 4) void node_mlp_kernel(
    const float* __restrict__ x, const float* __restrict__ msgs,
    const ushort* __restrict__ W1t, const float* __restrict__ b1,
    const float* __restrict__ g1, const float* __restrict__ be1,
    const ushort* __restrict__ W2t, const float* __restrict__ b2,
    float* __restrict__ x_out, ushort* __restrict__ xbf, int N)
{
    __shared__ ushort smem[64 * 264];           // in staged; h [64][136] aliases
    __shared__ float part_s[2][64], part_q[2][64];

    const int tid = threadIdx.x;
    const int row0 = blockIdx.x * 64;

    for (int idx = tid; idx < 64 * 64; idx += 256) {
        int r = idx >> 6, c4 = idx & 63;
        int row = row0 + r;
        float4 v = make_float4(0.f, 0.f, 0.f, 0.f);
        if (row < N)
            v = (c4 < 32) ? reinterpret_cast<const float4*>(x + (size_t)row * H)[c4]
                          : reinterpret_cast<const float4*>(msgs + (size_t)row * H)[c4 - 32];
        ushort4 bv;
        bv.x = f2bf(v.x); bv.y = f2bf(v.y); bv.z = f2bf(v.z); bv.w = f2bf(v.w);
        *reinterpret_cast<ushort4*>(&smem[r * 264 + c4 * 4]) = bv;
    }
    __syncthreads();

    const int lane = tid & 63, w = tid >> 6;
    const int l15 = lane & 15, lg = lane >> 4;
    const int mrow = (w & 1) * 32, ncol = (w >> 1) * 64;

    const ushort* pi0 = smem + (size_t)(mrow + l15) * 264;
    const ushort* pi1 = smem + (size_t)(mrow + 16 + l15) * 264;
    const ushort* pw1 = W1t + (size_t)(ncol + l15) * 256;

    f32x4 acc[2][4];
    #pragma unroll
    for (int mt = 0; mt < 2; ++mt)
        #pragma unroll
        for (int nt = 0; nt < 4; ++nt)
            acc[mt][nt] = (f32x4){0.f, 0.f, 0.f, 0.f};

    #pragma unroll
    for (int ks = 0; ks < 8; ++ks) {
        int k0 = ks * 32 + lg * 8;
        bf16x8 a0 = *reinterpret_cast<const bf16x8*>(pi0 + k0);
        bf16x8 a1 = *reinterpret_cast<const bf16x8*>(pi1 + k0);
        #pragma unroll
        for (int nt = 0; nt < 4; ++nt) {
            bf16x8 bfr = *reinterpret_cast<const bf16x8*>(pw1 + (size_t)nt * 16 * 256 + k0);
            acc[0][nt] = mfma16(a0, bfr, acc[0][nt]);
            acc[1][nt] = mfma16(a1, bfr, acc[1][nt]);
        }
    }

    float b1c[4], g1c[4], be1c[4];
    #pragma unroll
    for (int nt = 0; nt < 4; ++nt) {
        int c = ncol + nt * 16 + l15;
        b1c[nt] = b1[c]; g1c[nt] = g1[c]; be1c[nt] = be1[c];
    }
    #pragma unroll
    for (int mt = 0; mt < 2; ++mt)
        #pragma unroll
        for (int nt = 0; nt < 4; ++nt)
            #pragma unroll
            for (int r = 0; r < 4; ++r)
                acc[mt][nt][r] += b1c[nt];

    #pragma unroll
    for (int mt = 0; mt < 2; ++mt) {
        #pragma unroll
        for (int r = 0; r < 4; ++r) {
            float s = acc[mt][0][r] + acc[mt][1][r] + acc[mt][2][r] + acc[mt][3][r];
            float q = acc[mt][0][r] * acc[mt][0][r] + acc[mt][1][r] * acc[mt][1][r]
                    + acc[mt][2][r] * acc[mt][2][r] + acc[mt][3][r] * acc[mt][3][r];
            #pragma unroll
            for (int m = 8; m >= 1; m >>= 1) {
                s += __shfl_xor(s, m);
                q += __shfl_xor(q, m);
            }
            if (l15 == 0) {
                int rl = mrow + mt * 16 + lg * 4 + r;
                part_s[w >> 1][rl] = s;
                part_q[w >> 1][rl] = q;
            }
        }
    }
    __syncthreads();

    #pragma unroll
    for (int mt = 0; mt < 2; ++mt) {
        #pragma unroll
        for (int r = 0; r < 4; ++r) {
            int rl = mrow + mt * 16 + lg * 4 + r;
            float s  = part_s[0][rl] + part_s[1][rl];
            float q  = part_q[0][rl] + part_q[1][rl];
            float mu = s * (1.0f / H);
            float rs = rsqrtf(q * (1.0f / H) - mu * mu + LN_EPS);
            #pragma unroll
            for (int nt = 0; nt < 4; ++nt) {
                float v = (acc[mt][nt][r] - mu) * rs * g1c[nt] + be1c[nt];
                v = v / (1.0f + __expf(-v));
                smem[rl * 136 + ncol + nt * 16 + l15] = f2bf(v);
            }
        }
    }
    __syncthreads();

    const ushort* ph0 = smem + (size_t)(mrow + l15) * 136;
    const ushort* ph1 = smem + (size_t)(mrow + 16 + l15) * 136;
    const ushort* pw2 = W2t + (size_t)(ncol + l15) * 128;

    f32x4 acc2[2][4];
    #pragma unroll
    for (int nt = 0; nt < 4; ++nt) {
        float bb = b2[ncol + nt * 16 + l15];
        #pragma unroll
        for (int mt = 0; mt < 2; ++mt)
            acc2[mt][nt] = (f32x4){bb, bb, bb, bb};
    }
    #pragma unroll
    for (int ks = 0; ks < 4; ++ks) {
        int k0 = ks * 32 + lg * 8;
        bf16x8 a0 = *reinterpret_cast<const bf16x8*>(ph0 + k0);
        bf16x8 a1 = *reinterpret_cast<const bf16x8*>(ph1 + k0);
        #pragma unroll
        for (int nt = 0; nt < 4; ++nt) {
            bf16x8 bfr = *reinterpret_cast<const bf16x8*>(pw2 + (size_t)nt * 16 * 128 + k0);
            acc2[0][nt] = mfma16(a0, bfr, acc2[0][nt]);
            acc2[1][nt] = mfma16(a1, bfr, acc2[1][nt]);
        }
    }

    #pragma unroll
    for (int mt = 0; mt < 2; ++mt) {
        #pragma unroll
        for (int r = 0; r < 4; ++r) {
            int row = row0 + mrow + mt * 16 + lg * 4 + r;
            if (row < N) {
                const float* rp = x + (size_t)row * H;
                float* op = x_out + (size_t)row * H;
                ushort* bp = xbf + (size_t)row * H;
                #pragma unroll
                for (int nt = 0; nt < 4; ++nt) {
                    int c = ncol + nt * 16 + l15;
                    float o = acc2[mt][nt][r] + rp[c];
                    op[c] = o;
                    bp[c] = f2bf(o);
                }
            }
        }
    }
}

// ---------------------------------------------------------------------------
// Per-node precompute: Pa = x_out @ We1[0:128], Pb = x_out @ We1[128:256]
// (bf16 in/out, no bias).  Removes the per-edge gathered matmul k-steps.
// ---------------------------------------------------------------------------
__global__ __launch_bounds__(256, 4) void pmat_kernel(
    const ushort* __restrict__ xbf, const ushort* __restrict__ W1t,  // [128][384]
    ushort* __restrict__ Pa, ushort* __restrict__ Pb, int N)
{
    __shared__ ushort xs[64 * 136];

    const int tid = threadIdx.x;
    const int row0 = blockIdx.x * 64;

    for (int idx = tid; idx < 64 * 16; idx += 256) {
        int r = idx >> 4, c = idx & 15;
        int row = min(row0 + r, N - 1);
        *reinterpret_cast<bf16x8*>(&xs[r * 136 + c * 8]) =
            *reinterpret_cast<const bf16x8*>(xbf + (size_t)row * H + c * 8);
    }
    __syncthreads();

    const int lane = tid & 63, w = tid >> 6;
    const int l15 = lane & 15, lg = lane >> 4;
    const int mrow = (w & 1) * 32, ncol = (w >> 1) * 64;
    const int rA0 = mrow + l15, rA1 = mrow + 16 + l15;

    const ushort* px0 = xs + (size_t)rA0 * 136 + lg * 8;
    const ushort* px1 = xs + (size_t)rA1 * 136 + lg * 8;
    const ushort* pwa = W1t + (size_t)(ncol + l15) * 384 + lg * 8;        // k 0..127
    const ushort* pwb = pwa + 128;                                        // k 128..255

    f32x4 aa[2][4], ab[2][4];
    #pragma unroll
    for (int mt = 0; mt < 2; ++mt)
        #pragma unroll
        for (int nt = 0; nt < 4; ++nt) {
            aa[mt][nt] = (f32x4){0.f, 0.f, 0.f, 0.f};
            ab[mt][nt] = (f32x4){0.f, 0.f, 0.f, 0.f};
        }

    #pragma unroll
    for (int t = 0; t < 4; ++t) {
        bf16x8 a0 = *reinterpret_cast<const bf16x8*>(px0 + t * 32);
        bf16x8 a1 = *reinterpret_cast<const bf16x8*>(px1 + t * 32);
        #pragma unroll
        for (int nt = 0; nt < 4; ++nt) {
            bf16x8 ba = *reinterpret_cast<const bf16x8*>(pwa + (size_t)nt * 16 * 384 + t * 32);
            bf16x8 bb = *reinterpret_cast<const bf16x8*>(pwb + (size_t)nt * 16 * 384 + t * 32);
            aa[0][nt] = mfma16(a0, ba, aa[0][nt]);
            aa[1][nt] = mfma16(a1, ba, aa[1][nt]);
            ab[0][nt] = mfma16(a0, bb, ab[0][nt]);
            ab[1][nt] = mfma16(a1, bb, ab[1][nt]);
        }
    }

    #pragma unroll
    for (int mt = 0; mt < 2; ++mt) {
        #pragma unroll
        for (int r = 0; r < 4; ++r) {
            int row = row0 + mrow + mt * 16 + lg * 4 + r;
            if (row < N) {
                ushort* pa = Pa + (size_t)row * H;
                ushort* pb = Pb + (size_t)row * H;
                #pragma unroll
                for (int nt = 0; nt < 4; ++nt) {
                    int c = ncol + nt * 16 + l15;
                    pa[c] = f2bf(aa[mt][nt][r]);
                    pb[c] = f2bf(ab[mt][nt][r]);
                }
            }
        }
    }
}

// ---------------------------------------------------------------------------
// Edge MLP: h = Pa[s] + Pb[d] + e@W1c + b1 -> LN -> SiLU -> @W2 -> +e.
// Gathers are batched in the staging loop (summed into LDS); mm1 is a pure
// LDS K=128 matmul.  es buffer aliased with h after mm1.
// ---------------------------------------------------------------------------
__global__ __launch_bounds__(256, 4) void edge_mlp_kernel(
    const ushort* __restrict__ Pa, const ushort* __restrict__ Pb,
    const float* __restrict__ e, const int* __restrict__ ei,
    const ushort* __restrict__ W1t,  // [128][384]; e-part at k offset 256
    const float* __restrict__ b1,
    const float* __restrict__ g1, const float* __restrict__ be1,
    const ushort* __restrict__ W2t, const float* __restrict__ b2,
    float* __restrict__ e_out, int E)
{
    __shared__ ushort es[64 * 136];             // e bf16 (phase1) / h (phase2)
    __shared__ ushort ps[64 * 136];             // Pa[s]+Pb[d] bf16
    __shared__ float part_s[2][64], part_q[2][64];

    const int tid = threadIdx.x;
    const int row0 = blockIdx.x * 64;

    // ---- stage psum rows: ps[r] = Pa[s[r]] + Pb[d[r]]  (8 gathered 16B/thread)
    for (int idx = tid; idx < 64 * 16; idx += 256) {
        int r = idx >> 4, c = idx & 15;
        int rr = min(row0 + r, E - 1);
        int s = ei[rr], d = ei[E + rr];
        bf16x8 va = *reinterpret_cast<const bf16x8*>(Pa + (size_t)s * H + c * 8);
        bf16x8 vb = *reinterpret_cast<const bf16x8*>(Pb + (size_t)d * H + c * 8);
        bf16x8 o;
        #pragma unroll
        for (int j = 0; j < 8; ++j)
            o[j] = (short)f2bf(bf2f((ushort)va[j]) + bf2f((ushort)vb[j]));
        *reinterpret_cast<bf16x8*>(&ps[r * 136 + c * 8]) = o;
    }

    // ---- stage e rows -> bf16 LDS (coalesced float4) ----
    for (int idx = tid; idx < 64 * 32; idx += 256) {
        int r = idx >> 5, c4 = idx & 31;
        int row = row0 + r;
        float4 v = make_float4(0.f, 0.f, 0.f, 0.f);
        if (row < E)
            v = reinterpret_cast<const float4*>(e + (size_t)row * H)[c4];
        ushort4 bv;
        bv.x = f2bf(v.x); bv.y = f2bf(v.y); bv.z = f2bf(v.z); bv.w = f2bf(v.w);
        *reinterpret_cast<ushort4*>(&es[r * 136 + c4 * 4]) = bv;
    }
    __syncthreads();

    const int lane = tid & 63, w = tid >> 6;
    const int l15 = lane & 15, lg = lane >> 4;
    const int mrow = (w & 1) * 32, ncol = (w >> 1) * 64;
    const int rA0 = mrow + l15, rA1 = mrow + 16 + l15;

    const ushort* pe0 = es + (size_t)rA0 * 136 + lg * 8;
    const ushort* pe1 = es + (size_t)rA1 * 136 + lg * 8;
    const ushort* pw1 = W1t + (size_t)(ncol + l15) * 384 + 256 + lg * 8;  // e-part

    f32x4 acc[2][4];
    #pragma unroll
    for (int mt = 0; mt < 2; ++mt)
        #pragma unroll
        for (int nt = 0; nt < 4; ++nt)
            acc[mt][nt] = (f32x4){0.f, 0.f, 0.f, 0.f};

    // ---- mm1: e @ W1c  (K=128, pure LDS) ----
    #pragma unroll
    for (int t = 0; t < 4; ++t) {
        bf16x8 a0 = *reinterpret_cast<const bf16x8*>(pe0 + t * 32);
        bf16x8 a1 = *reinterpret_cast<const bf16x8*>(pe1 + t * 32);
        #pragma unroll
        for (int nt = 0; nt < 4; ++nt) {
            bf16x8 bfr = *reinterpret_cast<const bf16x8*>(pw1 + (size_t)nt * 16 * 384 + t * 32);
            acc[0][nt] = mfma16(a0, bfr, acc[0][nt]);
            acc[1][nt] = mfma16(a1, bfr, acc[1][nt]);
        }
    }

    // ---- + b1 + psum, LN stats ----
    float b1c[4], g1c[4], be1c[4];
    #pragma unroll
    for (int nt = 0; nt < 4; ++nt) {
        int c = ncol + nt * 16 + l15;
        b1c[nt] = b1[c]; g1c[nt] = g1[c]; be1c[nt] = be1[c];
    }
    #pragma unroll
    for (int mt = 0; mt < 2; ++mt)
        #pragma unroll
        for (int r = 0; r < 4; ++r) {
            int rl = mrow + mt * 16 + lg * 4 + r;
            #pragma unroll
            for (int nt = 0; nt < 4; ++nt)
                acc[mt][nt][r] += b1c[nt] + bf2f(ps[rl * 136 + ncol + nt * 16 + l15]);
        }

    #pragma unroll
    for (int mt = 0; mt < 2; ++mt) {
        #pragma unroll
        for (int r = 0; r < 4; ++r) {
            float s = acc[mt][0][r] + acc[mt][1][r] + acc[mt][2][r] + acc[mt][3][r];
            float q = acc[mt][0][r] * acc[mt][0][r] + acc[mt][1][r] * acc[mt][1][r]
                    + acc[mt][2][r] * acc[mt][2][r] + acc[mt][3][r] * acc[mt][3][r];
            #pragma unroll
            for (int m = 8; m >= 1; m >>= 1) {
                s += __shfl_xor(s, m);
                q += __shfl_xor(q, m);
            }
            if (l15 == 0) {
                int rl = mrow + mt * 16 + lg * 4 + r;
                part_s[w >> 1][rl] = s;
                part_q[w >> 1][rl] = q;
            }
        }
    }
    __syncthreads();   // separates e-reads from h-writes too

    // ---- LN + SiLU -> h (aliases es) ----
    #pragma unroll
    for (int mt = 0; mt < 2; ++mt) {
        #pragma unroll
        for (int r = 0; r < 4; ++r) {
            int rl = mrow + mt * 16 + lg * 4 + r;
            float s  = part_s[0][rl] + part_s[1][rl];
            float q  = part_q[0][rl] + part_q[1][rl];
            float mu = s * (1.0f / H);
            float rs = rsqrtf(q * (1.0f / H) - mu * mu + LN_EPS);
            #pragma unroll
            for (int nt = 0; nt < 4; ++nt) {
                float v = (acc[mt][nt][r] - mu) * rs * g1c[nt] + be1c[nt];
                v = v / (1.0f + __expf(-v));
                es[rl * 136 + ncol + nt * 16 + l15] = f2bf(v);
            }
        }
    }
    __syncthreads();

    // ---- mm2 ----
    const ushort* ph0 = es + (size_t)rA0 * 136;
    const ushort* ph1 = es + (size_t)rA1 * 136;
    const ushort* pw2 = W2t + (size_t)(ncol + l15) * 128;

    f32x4 acc2[2][4];
    #pragma unroll
    for (int nt = 0; nt < 4; ++nt) {
        float bb = b2[ncol + nt * 16 + l15];
        #pragma unroll
        for (int mt = 0; mt < 2; ++mt)
            acc2[mt][nt] = (f32x4){bb, bb, bb, bb};
    }
    #pragma unroll
    for (int ks = 0; ks < 4; ++ks) {
        int k0 = ks * 32 + lg * 8;
        bf16x8 a0 = *reinterpret_cast<const bf16x8*>(ph0 + k0);
        bf16x8 a1 = *reinterpret_cast<const bf16x8*>(ph1 + k0);
        #pragma unroll
        for (int nt = 0; nt < 4; ++nt) {
            bf16x8 bfr = *reinterpret_cast<const bf16x8*>(pw2 + (size_t)nt * 16 * 128 + k0);
            acc2[0][nt] = mfma16(a0, bfr, acc2[0][nt]);
            acc2[1][nt] = mfma16(a1, bfr, acc2[1][nt]);
        }
    }

    // ---- residual + store ----
    #pragma unroll
    for (int mt = 0; mt < 2; ++mt) {
        #pragma unroll
        for (int r = 0; r < 4; ++r) {
            int row = row0 + mrow + mt * 16 + lg * 4 + r;
            if (row < E) {
                const float* rp = e + (size_t)row * H;
                float* op = e_out + (size_t)row * H;
                #pragma unroll
                for (int nt = 0; nt < 4; ++nt) {
                    int c = ncol + nt * 16 + l15;
                    op[c] = acc2[mt][nt][r] + rp[c];
                }
            }
        }
    }
}

// ---------------------------------------------------------------------------
extern "C" void kernel_launch(void* const* d_in, const int* in_sizes, int n_in,
                              void* d_out, int out_size, void* d_ws, size_t ws_size,
                              hipStream_t stream)
{
    const float* x     = (const float*)d_in[0];
    const int*   ei    = (const int*)  d_in[1];
    const float* e     = (const float*)d_in[2];
    const float* Wn1   = (const float*)d_in[3];
    const float* bn1   = (const float*)d_in[4];
    const float* gn1   = (const float*)d_in[5];
    const float* betan1= (const float*)d_in[6];
    const float* Wn2   = (const float*)d_in[7];
    const float* bn2   = (const float*)d_in[8];
    const float* We1   = (const float*)d_in[9];
    const float* be1   = (const float*)d_in[10];
    const float* ge1   = (const float*)d_in[11];
    const float* betae1= (const float*)d_in[12];
    const float* We2   = (const float*)d_in[13];
    const float* be2   = (const float*)d_in[14];

    const int N = in_sizes[0] / H;
    const int E = in_sizes[2] / H;

    float* x_out = (float*)d_out;
    float* e_out = (float*)d_out + (long long)N * H;

    char* p = (char*)d_ws;
    float*  msgs = (float*)p;            p += (size_t)N * H * sizeof(float);
    ushort* xbf  = (ushort*)p;           p += (size_t)N * H * sizeof(ushort);
    ushort* Pa   = (ushort*)p;           p += (size_t)N * H * sizeof(ushort);
    ushort* Pb   = (ushort*)p;           p += (size_t)N * H * sizeof(ushort);
    ushort* Wn1t = (ushort*)p;           p += (size_t)256 * H * sizeof(ushort);
    ushort* Wn2t = (ushort*)p;           p += (size_t)H * H * sizeof(ushort);
    ushort* We1t = (ushort*)p;           p += (size_t)384 * H * sizeof(ushort);
    ushort* We2t = (ushort*)p;           p += (size_t)H * H * sizeof(ushort);
    p = (char*)(((size_t)p + 15) & ~(size_t)15);
    int* cnt    = (int*)p;               p += (size_t)N * sizeof(int);
    int* off    = (int*)p;               p += ((size_t)N + 1) * sizeof(int);
    int* cursor = (int*)p;               p += (size_t)N * sizeof(int);
    int* sorted = (int*)p;               p += (size_t)E * sizeof(int);

    wtrans_kernel<<<(256 * H + 255) / 256, 256, 0, stream>>>(Wn1, Wn1t, 256);
    wtrans_kernel<<<(H * H + 255) / 256, 256, 0, stream>>>(Wn2, Wn2t, H);
    wtrans_kernel<<<(384 * H + 255) / 256, 256, 0, stream>>>(We1, We1t, 384);
    wtrans_kernel<<<(H * H + 255) / 256, 256, 0, stream>>>(We2, We2t, H);

    hipMemsetAsync(cnt, 0, (size_t)N * sizeof(int), stream);
    hist_kernel<<<(E + 255) / 256, 256, 0, stream>>>(ei, cnt, E);
    scan_kernel<<<1, 1024, 0, stream>>>(cnt, off, cursor, N);
    reorder_kernel<<<(E + 255) / 256, 256, 0, stream>>>(ei, cursor, sorted, E);
    segsum_kernel<<<(N + 3) / 4, 256, 0, stream>>>(e, sorted, off, msgs, N);

    {
        int blocks = (N + 63) / 64;
        node_mlp_kernel<<<blocks, 256, 0, stream>>>(
            x, msgs, Wn1t, bn1, gn1, betan1, Wn2t, bn2, x_out, xbf, N);
    }
    {
        int blocks = (N + 63) / 64;
        pmat_kernel<<<blocks, 256, 0, stream>>>(xbf, We1t, Pa, Pb, N);
    }
    {
        int blocks = (E + 63) / 64;
        edge_mlp_kernel<<<blocks, 256, 0, stream>>>(
            Pa, Pb, e, ei, We1t, be1, ge1, betae1, We2t, be2, e_out, E);
    }
}